// Round 11
// baseline (244.100 us; speedup 1.0000x reference)
//
#include <hip/hip_runtime.h>
#include <hip/hip_bf16.h>
#include <stdint.h>

#define M_DIM 8192
#define N_DIM 4096
#define K_DIM 4096

#define BM 256
#define BN 256
#define BK 64                 // bytes of K per LDS tile = one mfma_i32_16x16x64_i8 K
#define NT (K_DIM / BK)       // 64 K-tiles
#define DEPTH 4               // circular LDS pipeline depth (A only, 4 x 16 KiB)

typedef int v4i __attribute__((ext_vector_type(4)));

#define AS1C(p) ((const __attribute__((address_space(1))) void*)(p))
#define AS3(p)  ((__attribute__((address_space(3))) void*)(p))

// ---------------------------------------------------------------------------
// Fused pack pass: int32 (int8-range) -> int8 for BOTH operands, one launch.
// ---------------------------------------------------------------------------
__device__ __forceinline__ int pack4(int a, int b, int c, int d) {
  return (a & 0xff) | ((b & 0xff) << 8) | ((c & 0xff) << 16) | (d << 24);
}

__global__ void pack_both_kernel(const int* __restrict__ x, const int* __restrict__ w,
                                 char* __restrict__ A8, char* __restrict__ B8,
                                 int nA, int nTot) {
  int idx = blockIdx.x * blockDim.x + threadIdx.x;
  int stride = gridDim.x * blockDim.x;
  for (int i = idx; i < nTot; i += stride) {
    const int4* pin;
    int4* pout;
    if (i < nA) {
      pin  = (const int4*)x + 4 * (size_t)i;
      pout = (int4*)A8 + i;
    } else {
      int j = i - nA;
      pin  = (const int4*)w + 4 * (size_t)j;
      pout = (int4*)B8 + j;
    }
    int4 v0 = pin[0];
    int4 v1 = pin[1];
    int4 v2 = pin[2];
    int4 v3 = pin[3];
    int4 o;
    o.x = pack4(v0.x, v0.y, v0.z, v0.w);
    o.y = pack4(v1.x, v1.y, v1.z, v1.w);
    o.z = pack4(v2.x, v2.y, v2.z, v2.w);
    o.w = pack4(v3.x, v3.y, v3.z, v3.w);
    *pout = o;
  }
}

// ---------------------------------------------------------------------------
// int8 GEMM: 256x256 tile, 8 waves (2Mx4N, per-wave 128x64), BK=64B,
// mfma_i32_16x16x64_i8.  R11 STRUCTURE: A staged via LDS ring (DEPTH=4,
// 64 KiB), B LOADED GLOBAL->REGISTER (no LDS for B at all):
//   per tile t:
//     BLOAD(t+1)  [4 x global_load_dwordx4 -> bf ping-pong set]
//     STAGE_A(t+3) [2 x global_load_lds]
//     READ_HI(t)   [4 ds_read]   ; MFMA_LO(t)   (aflo/bf resident)
//     READ_ALO(t+1)[4 ds_read]   ; MFMA_HI(t)
//     s_waitcnt vmcnt(2); s_barrier
// B frag = per-lane slice B8[(bn+wc*64+nj*16+frow)*4096 + t*64 + fchunk*16]
// (identical bytes to the old LDS path, verified via the swizzle identity).
// Cuts per-CU/tile LDS traffic from 96 KB reads + 32 KB writes to
// 64 KB reads + 16 KB writes -> LDS well under the MFMA pipe.
//
// Wait math: end-of-tile vmcnt(2) keeps only STAGE_A(t+3) in flight =>
// bload(t+1) and stage(t+2) landed; so next tile's MFMA operands and the
// A-reads of t+2 are safe.  STAGE_A(t+3) overwrites buf[(t-1)&3]: all
// reads of t-1 completed before t-1's MFMA clusters and its end barrier.
// ---------------------------------------------------------------------------
__global__ __launch_bounds__(512, 2) void gemm_i8_kernel(
    const char* __restrict__ A8, const char* __restrict__ B8,
    const int* __restrict__ bias, const float* __restrict__ alpha_p,
    const float* __restrict__ beta_p, int* __restrict__ out) {
  __shared__ alignas(16) char lds[DEPTH][BM * BK];  // 4 x 16 KiB = 64 KiB (A only)

  const int tid  = threadIdx.x;
  const int lane = tid & 63;
  const int wave = tid >> 6;

  // XCD-aware bijective swizzle: 512 blocks, 64 consecutive per XCD.
  const int orig = blockIdx.x;
  const int swz  = (orig & 7) * (512 / 8) + (orig >> 3);
  const int bm   = (swz >> 4) * BM;  // 32 row-tiles
  const int bn   = (swz & 15) * BN;  // 16 col-tiles

  // A staging: tile 16 KB = 2 rounds x 512 thr x 16 B.
  // Pre-swizzled global chunk g = p ^ ((row>>1)&3) (both-sides swizzle).
  int aoff[2], ldsoff[2];
#pragma unroll
  for (int i = 0; i < 2; ++i) {
    int linear = i * 8192 + tid * 16;
    int row = linear >> 6;           // 64 B rows
    int p   = (linear >> 4) & 3;
    int g   = p ^ ((row >> 1) & 3);
    ldsoff[i] = i * 8192 + wave * 1024;       // wave-uniform LDS base
    aoff[i] = (bm + row) * K_DIM + g * 16;
  }

#define STAGE_A(t)                                                                  \
  do {                                                                              \
    const char* ab_ = A8 + (size_t)(t) * BK;                                        \
    char* base_ = &lds[(t) & (DEPTH - 1)][0];                                       \
    _Pragma("unroll") for (int i_ = 0; i_ < 2; ++i_)                                \
      __builtin_amdgcn_global_load_lds(AS1C(ab_ + aoff[i_]),                        \
                                       AS3(base_ + ldsoff[i_]), 16, 0, 0);          \
  } while (0)

  v4i acc[8][4];
#pragma unroll
  for (int i = 0; i < 8; ++i)
#pragma unroll
    for (int j = 0; j < 4; ++j) acc[i][j] = (v4i){0, 0, 0, 0};

  const int wr = wave >> 2;         // 0..1 (M half: 128 rows)
  const int wc = wave & 3;          // 0..3 (N quarter: 64 cols)
  const int frow = lane & 15;
  const int fchunk = lane >> 4;
  // swizzle XOR depends only on frow (rows differ by multiples of 16) -> lane-const
  const int swzoff = ((fchunk ^ ((frow >> 1) & 3)) << 4);

  // B global fragment base: row (bn + wc*64 + frow), chunk fchunk.
  const char* Bgp = B8 + (size_t)((bn + wc * 64 + frow) * K_DIM + fchunk * 16);

  // Ping-pong fragment sets (static names, rule #20) + shared afhi.
  v4i bf0[4], aflo0[4], bf1[4], aflo1[4], afhi[4];

#define BLOAD(S, t)                                                                 \
  do {                                                                              \
    _Pragma("unroll") for (int nj = 0; nj < 4; ++nj)                                \
      bf##S[nj] = *(const v4i*)(Bgp + nj * (16 * K_DIM) + (t) * 64);                \
  } while (0)

#define READ_ALO(S, t)                                                              \
  do {                                                                              \
    const char* base_ = &lds[(t) & (DEPTH - 1)][0];                                 \
    _Pragma("unroll") for (int mi = 0; mi < 4; ++mi)                                \
      aflo##S[mi] = *(const v4i*)(base_ + (wr * 128 + mi * 16 + frow) * 64 +        \
                                  swzoff);                                          \
  } while (0)

#define READ_HI(t)                                                                  \
  do {                                                                              \
    const char* base_ = &lds[(t) & (DEPTH - 1)][0];                                 \
    _Pragma("unroll") for (int mi = 0; mi < 4; ++mi)                                \
      afhi[mi] = *(const v4i*)(base_ + (wr * 128 + (mi + 4) * 16 + frow) * 64 +     \
                               swzoff);                                             \
  } while (0)

#define MFMA_LO(S)                                                                  \
  do {                                                                              \
    __builtin_amdgcn_s_setprio(1);                                                  \
    _Pragma("unroll") for (int mi = 0; mi < 4; ++mi)                                \
      _Pragma("unroll") for (int nj = 0; nj < 4; ++nj)                              \
        acc[mi][nj] = __builtin_amdgcn_mfma_i32_16x16x64_i8(aflo##S[mi], bf##S[nj], \
                                                            acc[mi][nj], 0, 0, 0); \
    __builtin_amdgcn_s_setprio(0);                                                  \
  } while (0)

#define MFMA_HI(S)                                                                  \
  do {                                                                              \
    __builtin_amdgcn_s_setprio(1);                                                  \
    _Pragma("unroll") for (int mi = 0; mi < 4; ++mi)                                \
      _Pragma("unroll") for (int nj = 0; nj < 4; ++nj)                              \
        acc[mi + 4][nj] = __builtin_amdgcn_mfma_i32_16x16x64_i8(afhi[mi], bf##S[nj],\
                                                                acc[mi + 4][nj],   \
                                                                0, 0, 0);          \
    __builtin_amdgcn_s_setprio(0);                                                  \
  } while (0)

// EV: 2 = vmcnt(2)+barrier, 0 = vmcnt(0)+barrier, -1 = nothing (tail).
#define TILE(t, C, N, DOBL, DOSTG, EV)                                              \
  do {                                                                              \
    if (DOBL) BLOAD(N, (t) + 1);                                                    \
    if (DOSTG) STAGE_A((t) + 3);                                                    \
    READ_HI(t);                                                                     \
    MFMA_LO(C);                                                                     \
    if ((t) + 1 < NT) READ_ALO(N, (t) + 1);                                         \
    MFMA_HI(C);                                                                     \
    if ((EV) == 2) asm volatile("s_waitcnt vmcnt(2)" ::: "memory");                 \
    if ((EV) == 0) asm volatile("s_waitcnt vmcnt(0)" ::: "memory");                 \
    if ((EV) >= 0) __builtin_amdgcn_s_barrier();                                    \
  } while (0)

  // Prologue: stage A tiles 0..2 (6 vm), load B tile 0 (4 vm);
  // vmcnt(4) -> A0..A2 landed (B0 guarded by compiler's operand wait).
  STAGE_A(0);
  STAGE_A(1);
  STAGE_A(2);
  BLOAD(0, 0);
  asm volatile("s_waitcnt vmcnt(4)" ::: "memory");
  __builtin_amdgcn_s_barrier();
  READ_ALO(0, 0);

  for (int t = 0; t < NT - 4; t += 2) {   // t = 0..58: stages 3..61, bloads 1..60
    TILE(t, 0, 1, true, true, 2);
    TILE(t + 1, 1, 0, true, true, 2);
  }
  TILE(NT - 4, 0, 1, true, true, 2);      // t=60: stage 63, bload 61
  TILE(NT - 3, 1, 0, true, false, 0);     // t=61: bload 62; vmcnt(0)
  TILE(NT - 2, 0, 1, true, false, 0);     // t=62: bload 63; vmcnt(0)
  TILE(NT - 1, 1, 0, false, false, -1);   // t=63

  // Epilogue: D = rint(alpha*acc + beta*bias[n]).
  // C/D layout (16x16): col = lane&15, row = (lane>>4)*4 + reg.
  const float alpha = *alpha_p;
  const float beta  = *beta_p;
  const int col0 = bn + wc * 64 + frow;
  float bb4[4];
#pragma unroll
  for (int nj = 0; nj < 4; ++nj) bb4[nj] = beta * (float)bias[col0 + nj * 16];

  const int rbase = bm + wr * 128 + (lane >> 4) * 4;
#pragma unroll
  for (int mi = 0; mi < 8; ++mi) {
#pragma unroll
    for (int r = 0; r < 4; ++r) {
      size_t rowoff = (size_t)(rbase + mi * 16 + r) * N_DIM;
#pragma unroll
      for (int nj = 0; nj < 4; ++nj) {
        out[rowoff + col0 + nj * 16] =
            (int)rintf(fmaf(alpha, (float)acc[mi][nj][r], bb4[nj]));
      }
    }
  }
#undef STAGE_A
#undef BLOAD
#undef READ_ALO
#undef READ_HI
#undef MFMA_LO
#undef MFMA_HI
#undef TILE
}

// ---------------------------------------------------------------------------
// Safety fallback if ws is too small for the packed operands (slow but right).
// ---------------------------------------------------------------------------
__global__ void naive_kernel(const int* __restrict__ x, const int* __restrict__ w,
                             const int* __restrict__ bias,
                             const float* __restrict__ alpha_p,
                             const float* __restrict__ beta_p,
                             int* __restrict__ out) {
  size_t idx = (size_t)blockIdx.x * 256 + threadIdx.x;
  int m = (int)(idx / N_DIM);
  int n = (int)(idx % N_DIM);
  const int4* xr = (const int4*)(x + (size_t)m * K_DIM);
  const int4* wr = (const int4*)(w + (size_t)n * K_DIM);
  int acc = 0;
  for (int k = 0; k < K_DIM / 4; ++k) {
    int4 a = xr[k];
    int4 b = wr[k];
    acc += a.x * b.x + a.y * b.y + a.z * b.z + a.w * b.w;
  }
  out[idx] = (int)rintf(fmaf(*alpha_p, (float)acc, (*beta_p) * (float)bias[n]));
}

extern "C" void kernel_launch(void* const* d_in, const int* in_sizes, int n_in,
                              void* d_out, int out_size, void* d_ws, size_t ws_size,
                              hipStream_t stream) {
  const int*   x     = (const int*)d_in[0];
  const int*   w     = (const int*)d_in[1];
  const int*   bias  = (const int*)d_in[2];
  const float* alpha = (const float*)d_in[3];
  const float* beta  = (const float*)d_in[4];
  int* out = (int*)d_out;

  const size_t a8_bytes = (size_t)M_DIM * K_DIM;  // 32 MiB
  const size_t b8_bytes = (size_t)N_DIM * K_DIM;  // 16 MiB

  if (ws_size >= a8_bytes + b8_bytes) {
    char* A8 = (char*)d_ws;
    char* B8 = A8 + a8_bytes;
    const int nA = (int)(a8_bytes / 16);
    const int nTot = (int)((a8_bytes + b8_bytes) / 16);
    pack_both_kernel<<<2048, 256, 0, stream>>>(x, w, A8, B8, nA, nTot);
    const int nblk = (M_DIM / BM) * (N_DIM / BN);  // 32*16 = 512
    gemm_i8_kernel<<<nblk, 512, 0, stream>>>(A8, B8, bias, alpha, beta, out);
  } else {
    naive_kernel<<<(M_DIM * (size_t)N_DIM) / 256, 256, 0, stream>>>(x, w, bias, alpha, beta, out);
  }
}

// Round 12
// 180.185 us; speedup vs baseline: 1.3547x; 1.3547x over previous
//
#include <hip/hip_runtime.h>
#include <hip/hip_bf16.h>
#include <stdint.h>

#define M_DIM 8192
#define N_DIM 4096
#define K_DIM 4096

#define BM 256
#define BN 256
#define BK 64                 // bytes of K per LDS tile = one mfma_i32_16x16x64_i8 K
#define NT (K_DIM / BK)       // 64 K-tiles
#define DEPTH 4               // circular LDS pipeline depth

typedef int v4i __attribute__((ext_vector_type(4)));

#define AS1C(p) ((const __attribute__((address_space(1))) void*)(p))
#define AS3(p)  ((__attribute__((address_space(3))) void*)(p))

// ---------------------------------------------------------------------------
// Fused pack pass: int32 (int8-range) -> int8 for BOTH operands, one launch.
// ---------------------------------------------------------------------------
__device__ __forceinline__ int pack4(int a, int b, int c, int d) {
  return (a & 0xff) | ((b & 0xff) << 8) | ((c & 0xff) << 16) | (d << 24);
}

__global__ void pack_both_kernel(const int* __restrict__ x, const int* __restrict__ w,
                                 char* __restrict__ A8, char* __restrict__ B8,
                                 int nA, int nTot) {
  int idx = blockIdx.x * blockDim.x + threadIdx.x;
  int stride = gridDim.x * blockDim.x;
  for (int i = idx; i < nTot; i += stride) {
    const int4* pin;
    int4* pout;
    if (i < nA) {
      pin  = (const int4*)x + 4 * (size_t)i;
      pout = (int4*)A8 + i;
    } else {
      int j = i - nA;
      pin  = (const int4*)w + 4 * (size_t)j;
      pout = (int4*)B8 + j;
    }
    int4 v0 = pin[0];
    int4 v1 = pin[1];
    int4 v2 = pin[2];
    int4 v3 = pin[3];
    int4 o;
    o.x = pack4(v0.x, v0.y, v0.z, v0.w);
    o.y = pack4(v1.x, v1.y, v1.z, v1.w);
    o.z = pack4(v2.x, v2.y, v2.z, v2.w);
    o.w = pack4(v3.x, v3.y, v3.z, v3.w);
    *pout = o;
  }
}

// ---------------------------------------------------------------------------
// int8 GEMM: 256x256 tile, 8 waves (2Mx4N, per-wave 128x64), BK=64B,
// mfma_i32_16x16x64_i8, DEPTH=4 LDS ring, counted vmcnt (4/0), ONE barrier
// per K-tile, cross-tile register prefetch (R8 structure — best measured:
// 131 us GEMM, MfmaUtil 48.4%).  This round: setprio REMOVED (m190: hurts
// lockstep GEMM).
//
//   TILE(t): STAGE_A(t+3); READ afhi(t)      [4 ds]; MFMA_LO(t)
//            STAGE_B(t+3); READ bf/aflo(t+1) [8 ds]; MFMA_HI(t)
//            s_waitcnt vmcnt(4); s_barrier
//
// Wait math (4 gloads per tile per thread): end-of-t outstanding =
// {t+2 (4), t+3 (4)}; vmcnt(4) -> t+2 landed => READ(t+2) during t+1 is
// proven.  STAGE_*(t+3) overwrites buf[(t-1)&3]: every wave's reads of
// t-1 completed before its t-1 MFMA clusters (compiler operand waits),
// which precede the end-of-(t-1) barrier.
// ---------------------------------------------------------------------------
__global__ __launch_bounds__(512, 2) void gemm_i8_kernel(
    const char* __restrict__ A8, const char* __restrict__ B8,
    const int* __restrict__ bias, const float* __restrict__ alpha_p,
    const float* __restrict__ beta_p, int* __restrict__ out) {
  __shared__ alignas(16) char lds[DEPTH][BM * BK + BN * BK];  // 4 x 32 KiB

  const int tid  = threadIdx.x;
  const int lane = tid & 63;
  const int wave = tid >> 6;

  // XCD-aware bijective swizzle: 512 blocks, 64 consecutive per XCD.
  const int orig = blockIdx.x;
  const int swz  = (orig & 7) * (512 / 8) + (orig >> 3);
  const int bm   = (swz >> 4) * BM;  // 32 row-tiles
  const int bn   = (swz & 15) * BN;  // 16 col-tiles

  // Staging geometry: per operand tile 16 KB = 2 rounds x 512 thr x 16 B.
  // Pre-swizzled global chunk g = p ^ ((row>>1)&3) (both-sides swizzle).
  int aoff[2], boff[2], ldsoff[2];
#pragma unroll
  for (int i = 0; i < 2; ++i) {
    int linear = i * 8192 + tid * 16;
    int row = linear >> 6;           // 64 B rows
    int p   = (linear >> 4) & 3;
    int g   = p ^ ((row >> 1) & 3);
    ldsoff[i] = i * 8192 + wave * 1024;       // wave-uniform LDS base
    aoff[i] = (bm + row) * K_DIM + g * 16;
    boff[i] = (bn + row) * K_DIM + g * 16;
  }

#define STAGE_A(t)                                                                  \
  do {                                                                              \
    const char* ab_ = A8 + (size_t)(t) * BK;                                        \
    char* base_ = &lds[(t) & (DEPTH - 1)][0];                                       \
    _Pragma("unroll") for (int i_ = 0; i_ < 2; ++i_)                                \
      __builtin_amdgcn_global_load_lds(AS1C(ab_ + aoff[i_]),                        \
                                       AS3(base_ + ldsoff[i_]), 16, 0, 0);          \
  } while (0)

#define STAGE_B(t)                                                                  \
  do {                                                                              \
    const char* bb_ = B8 + (size_t)(t) * BK;                                        \
    char* base_ = &lds[(t) & (DEPTH - 1)][0];                                       \
    _Pragma("unroll") for (int i_ = 0; i_ < 2; ++i_)                                \
      __builtin_amdgcn_global_load_lds(AS1C(bb_ + boff[i_]),                        \
                                       AS3(base_ + 16384 + ldsoff[i_]), 16, 0, 0);  \
  } while (0)

  v4i acc[8][4];
#pragma unroll
  for (int i = 0; i < 8; ++i)
#pragma unroll
    for (int j = 0; j < 4; ++j) acc[i][j] = (v4i){0, 0, 0, 0};

  const int wr = wave >> 2;         // 0..1 (M half: 128 rows)
  const int wc = wave & 3;          // 0..3 (N quarter: 64 cols)
  const int frow = lane & 15;
  const int fchunk = lane >> 4;
  // swizzle XOR depends only on frow (rows differ by multiples of 16) -> lane-const
  const int swzoff = ((fchunk ^ ((frow >> 1) & 3)) << 4);

  // Ping-pong lo-fragment sets (static names, rule #20) + shared afhi.
  v4i bf0[4], aflo0[4], bf1[4], aflo1[4], afhi[4];

#define READ0(S, t)                                                                 \
  do {                                                                              \
    const char* base_ = &lds[(t) & (DEPTH - 1)][0];                                 \
    _Pragma("unroll") for (int nj = 0; nj < 4; ++nj)                                \
      bf##S[nj] = *(const v4i*)(base_ + 16384 + (wc * 64 + nj * 16 + frow) * 64 +   \
                                swzoff);                                            \
    _Pragma("unroll") for (int mi = 0; mi < 4; ++mi)                                \
      aflo##S[mi] = *(const v4i*)(base_ + (wr * 128 + mi * 16 + frow) * 64 +        \
                                  swzoff);                                          \
  } while (0)

#define READ1(t)                                                                    \
  do {                                                                              \
    const char* base_ = &lds[(t) & (DEPTH - 1)][0];                                 \
    _Pragma("unroll") for (int mi = 0; mi < 4; ++mi)                                \
      afhi[mi] = *(const v4i*)(base_ + (wr * 128 + (mi + 4) * 16 + frow) * 64 +     \
                               swzoff);                                             \
  } while (0)

#define MFMA_LO(S)                                                                  \
  do {                                                                              \
    _Pragma("unroll") for (int mi = 0; mi < 4; ++mi)                                \
      _Pragma("unroll") for (int nj = 0; nj < 4; ++nj)                              \
        acc[mi][nj] = __builtin_amdgcn_mfma_i32_16x16x64_i8(aflo##S[mi], bf##S[nj], \
                                                            acc[mi][nj], 0, 0, 0); \
  } while (0)

#define MFMA_HI(S)                                                                  \
  do {                                                                              \
    _Pragma("unroll") for (int mi = 0; mi < 4; ++mi)                                \
      _Pragma("unroll") for (int nj = 0; nj < 4; ++nj)                              \
        acc[mi + 4][nj] = __builtin_amdgcn_mfma_i32_16x16x64_i8(afhi[mi], bf##S[nj],\
                                                                acc[mi + 4][nj],   \
                                                                0, 0, 0);          \
  } while (0)

// EV: 4 = vmcnt(4)+barrier, 0 = vmcnt(0)+barrier, -1 = nothing (tail).
#define TILE(t, C, N, STG, EV)                                                      \
  do {                                                                              \
    if (STG) STAGE_A((t) + 3);                                                      \
    READ1(t);                                                                       \
    MFMA_LO(C);                                                                     \
    if (STG) STAGE_B((t) + 3);                                                      \
    if ((t) + 1 < NT) READ0(N, (t) + 1);                                            \
    MFMA_HI(C);                                                                     \
    if ((EV) == 4) asm volatile("s_waitcnt vmcnt(4)" ::: "memory");                 \
    if ((EV) == 0) asm volatile("s_waitcnt vmcnt(0)" ::: "memory");                 \
    if ((EV) >= 0) __builtin_amdgcn_s_barrier();                                    \
  } while (0)

  // Prologue: stage tiles 0..2; vmcnt(4) -> tiles 0,1 landed; read tile-0 frags.
  STAGE_A(0); STAGE_B(0);
  STAGE_A(1); STAGE_B(1);
  STAGE_A(2); STAGE_B(2);
  asm volatile("s_waitcnt vmcnt(4)" ::: "memory");
  __builtin_amdgcn_s_barrier();
  READ0(0, 0);

  for (int t = 0; t < NT - 4; t += 2) {   // t = 0..58: stages 3..62
    TILE(t, 0, 1, true, 4);
    TILE(t + 1, 1, 0, true, 4);
  }
  TILE(NT - 4, 0, 1, true, 4);            // t=60: stages tile 63
  TILE(NT - 3, 1, 0, false, 0);           // t=61: vmcnt(0) -> tile 63 landed
  TILE(NT - 2, 0, 1, false, -1);          // t=62: reads tile 63 frags
  TILE(NT - 1, 1, 0, false, -1);          // t=63

  // Epilogue: D = rint(alpha*acc + beta*bias[n]).
  // C/D layout (16x16): col = lane&15, row = (lane>>4)*4 + reg.
  const float alpha = *alpha_p;
  const float beta  = *beta_p;
  const int col0 = bn + wc * 64 + frow;
  float bb4[4];
#pragma unroll
  for (int nj = 0; nj < 4; ++nj) bb4[nj] = beta * (float)bias[col0 + nj * 16];

  const int rbase = bm + wr * 128 + (lane >> 4) * 4;
#pragma unroll
  for (int mi = 0; mi < 8; ++mi) {
#pragma unroll
    for (int r = 0; r < 4; ++r) {
      size_t rowoff = (size_t)(rbase + mi * 16 + r) * N_DIM;
#pragma unroll
      for (int nj = 0; nj < 4; ++nj) {
        out[rowoff + col0 + nj * 16] =
            (int)rintf(fmaf(alpha, (float)acc[mi][nj][r], bb4[nj]));
      }
    }
  }
#undef STAGE_A
#undef STAGE_B
#undef READ0
#undef READ1
#undef MFMA_LO
#undef MFMA_HI
#undef TILE
}

// ---------------------------------------------------------------------------
// Safety fallback if ws is too small for the packed operands (slow but right).
// ---------------------------------------------------------------------------
__global__ void naive_kernel(const int* __restrict__ x, const int* __restrict__ w,
                             const int* __restrict__ bias,
                             const float* __restrict__ alpha_p,
                             const float* __restrict__ beta_p,
                             int* __restrict__ out) {
  size_t idx = (size_t)blockIdx.x * 256 + threadIdx.x;
  int m = (int)(idx / N_DIM);
  int n = (int)(idx % N_DIM);
  const int4* xr = (const int4*)(x + (size_t)m * K_DIM);
  const int4* wr = (const int4*)(w + (size_t)n * K_DIM);
  int acc = 0;
  for (int k = 0; k < K_DIM / 4; ++k) {
    int4 a = xr[k];
    int4 b = wr[k];
    acc += a.x * b.x + a.y * b.y + a.z * b.z + a.w * b.w;
  }
  out[idx] = (int)rintf(fmaf(*alpha_p, (float)acc, (*beta_p) * (float)bias[n]));
}

extern "C" void kernel_launch(void* const* d_in, const int* in_sizes, int n_in,
                              void* d_out, int out_size, void* d_ws, size_t ws_size,
                              hipStream_t stream) {
  const int*   x     = (const int*)d_in[0];
  const int*   w     = (const int*)d_in[1];
  const int*   bias  = (const int*)d_in[2];
  const float* alpha = (const float*)d_in[3];
  const float* beta  = (const float*)d_in[4];
  int* out = (int*)d_out;

  const size_t a8_bytes = (size_t)M_DIM * K_DIM;  // 32 MiB
  const size_t b8_bytes = (size_t)N_DIM * K_DIM;  // 16 MiB

  if (ws_size >= a8_bytes + b8_bytes) {
    char* A8 = (char*)d_ws;
    char* B8 = A8 + a8_bytes;
    const int nA = (int)(a8_bytes / 16);
    const int nTot = (int)((a8_bytes + b8_bytes) / 16);
    pack_both_kernel<<<2048, 256, 0, stream>>>(x, w, A8, B8, nA, nTot);
    const int nblk = (M_DIM / BM) * (N_DIM / BN);  // 32*16 = 512
    gemm_i8_kernel<<<nblk, 512, 0, stream>>>(A8, B8, bias, alpha, beta, out);
  } else {
    naive_kernel<<<(M_DIM * (size_t)N_DIM) / 256, 256, 0, stream>>>(x, w, bias, alpha, beta, out);
  }
}